// Round 8
// baseline (71.472 us; speedup 1.0000x reference)
//
#include <hip/hip_runtime.h>

#define NB 8
#define NS 2048
#define ND 1024
#define NE 8

typedef unsigned short ushort_t;
typedef __attribute__((ext_vector_type(8))) short bf16x8;
typedef __attribute__((ext_vector_type(4))) float f32x4;

__device__ __forceinline__ unsigned short f2bf(float f) {
    union { float f; unsigned int u; } x; x.f = f;
    unsigned int u = x.u + 0x7fffu + ((x.u >> 16) & 1u);
    return (unsigned short)(u >> 16);
}

__device__ __forceinline__ void gload16(const void* g, void* l) {
    __builtin_amdgcn_global_load_lds(
        (const __attribute__((address_space(1))) unsigned int*)g,
        (__attribute__((address_space(3))) unsigned int*)l, 16, 0, 0);
}

// local top-k gate coefs for one batch row (deterministic tie-break = first index)
__device__ __forceinline__ void coef_local(const float* __restrict__ scores,
                                           int b, int k, float* cf) {
    float s[NE];
#pragma unroll
    for (int e = 0; e < NE; ++e) s[e] = scores[b * NE + e];
    bool sel[NE];
#pragma unroll
    for (int e = 0; e < NE; ++e) sel[e] = false;
    float sum = 0.f;
    for (int j = 0; j < k; ++j) {
        int best = 0; float bv = -3.4e38f;
#pragma unroll
        for (int e = 0; e < NE; ++e)
            if (!sel[e] && s[e] > bv) { bv = s[e]; best = e; }
        sel[best] = true; sum += bv;
    }
    float scale = 1.f / (sum + 1e-8f);
#pragma unroll
    for (int e = 0; e < NE; ++e) cf[e] = sel[e] ? scale * s[e] : 0.f;
}

// ====== fused prep: combine (2048 blk) | convert (8192 blk) | bias (32) | routing (1) ======
__global__ void prep_kernel(const float* __restrict__ x,
                            const float* __restrict__ scores,
                            const float* __restrict__ W,
                            const float* __restrict__ eb,
                            const int* __restrict__ kp,
                            ushort_t* __restrict__ xb,
                            ushort_t* __restrict__ wct,
                            float* __restrict__ bias,
                            float* __restrict__ counts) {
    __shared__ float tile[64][65];
    __shared__ int selS[NB][NE];
    int bid = blockIdx.x;
    int t = threadIdx.x;

    if (bid < 2048) {
        int b = bid >> 8;
        int f0 = (bid & 15) * 64, d0 = ((bid >> 4) & 15) * 64;
        float cf[NE];
        coef_local(scores, b, kp[0], cf);
        int lr = t >> 4;
        int lc = (t & 15) * 4;
        float4 acc[4];
#pragma unroll
        for (int it = 0; it < 4; ++it) acc[it] = make_float4(0.f, 0.f, 0.f, 0.f);
#pragma unroll
        for (int e = 0; e < NE; ++e) {
            float c = cf[e];
            if (c != 0.f) {
                const float* We = W + ((size_t)e * ND * ND);
#pragma unroll
                for (int it = 0; it < 4; ++it) {
                    int d = d0 + lr + it * 16;
                    float4 v = *(const float4*)(We + (size_t)d * ND + f0 + lc);
                    acc[it].x += c * v.x; acc[it].y += c * v.y;
                    acc[it].z += c * v.z; acc[it].w += c * v.w;
                }
            }
        }
#pragma unroll
        for (int it = 0; it < 4; ++it) {
            int r = lr + it * 16;
            tile[r][lc + 0] = acc[it].x; tile[r][lc + 1] = acc[it].y;
            tile[r][lc + 2] = acc[it].z; tile[r][lc + 3] = acc[it].w;
        }
        __syncthreads();
        int dl = t & 63;
        int frow = t >> 6;
        ushort_t* dst = wct + (size_t)b * ND * ND + (size_t)f0 * ND + d0 + dl;
#pragma unroll
        for (int it = 0; it < 16; ++it) {
            int f = frow + it * 4;
            dst[(size_t)f * ND] = f2bf(tile[dl][f]);
        }
    } else if (bid < 10240) {
        size_t i = (size_t)(bid - 2048) * 256 + t;
        const float4* p = (const float4*)x + 2 * i;
        float4 a = p[0], b = p[1];
        uint4 o;
        o.x = (unsigned)f2bf(a.x) | ((unsigned)f2bf(a.y) << 16);
        o.y = (unsigned)f2bf(a.z) | ((unsigned)f2bf(a.w) << 16);
        o.z = (unsigned)f2bf(b.x) | ((unsigned)f2bf(b.y) << 16);
        o.w = (unsigned)f2bf(b.z) | ((unsigned)f2bf(b.w) << 16);
        ((uint4*)xb)[i] = o;
    } else if (bid < 10272) {
        int i = bid - 10240;
        int b = i >> 2, f = (i & 3) * 256 + t;
        float cf[NE];
        coef_local(scores, b, kp[0], cf);
        float acc = 0.f;
#pragma unroll
        for (int e = 0; e < NE; ++e)
            if (cf[e] != 0.f) acc += cf[e] * eb[e * ND + f];
        bias[b * ND + f] = acc;
    } else {
        int k = kp[0];
        if (t < NB) {
            float s[NE];
#pragma unroll
            for (int e = 0; e < NE; ++e) s[e] = scores[t * NE + e];
            bool sel[NE];
#pragma unroll
            for (int e = 0; e < NE; ++e) sel[e] = false;
            for (int j = 0; j < k; ++j) {
                int best = 0; float bv = -3.4e38f;
#pragma unroll
                for (int e = 0; e < NE; ++e)
                    if (!sel[e] && s[e] > bv) { bv = s[e]; best = e; }
                sel[best] = true;
            }
#pragma unroll
            for (int e = 0; e < NE; ++e) selS[t][e] = sel[e] ? 1 : 0;
        }
        __syncthreads();
        if (t < NE) {
            int c = 0;
#pragma unroll
            for (int b = 0; b < NB; ++b) c += selS[b][t];
            counts[t] = (float)c;
        }
    }
}

// ====== 256x256 8-wave GEMM, BK=64, 2dbuf x 2 K-half LDS, 4 fine phases/tile ======
// Per phase: <=8 ds_read_b128 + 1 half-tile stage (2 gloads) + barrier/lgkm0/16 MFMA/barrier.
// vmcnt(8) counted at end-ph1/ph3 only; stages land >=4 phases after issue. 128 KiB LDS.
__global__ __launch_bounds__(512, 2) void gemm_kernel(const ushort_t* __restrict__ xb,
                                                      const ushort_t* __restrict__ wct,
                                                      const float* __restrict__ bias,
                                                      float* __restrict__ out) {
    __shared__ ushort_t ldsA[2][2][256 * 32];   // [dbuf][khalf] 16 KiB each
    __shared__ ushort_t ldsB[2][2][256 * 32];

    int bid = blockIdx.x;
    int b = bid & 7;                 // batch -> XCD
    int tile = bid >> 3;             // 0..31
    int m0 = (tile >> 2) * 256;
    int n0 = (tile & 3) * 256;
    const ushort_t* A  = xb  + ((size_t)b * NS * ND) + (size_t)m0 * ND;
    const ushort_t* Bt = wct + ((size_t)b * ND * ND) + (size_t)n0 * ND;

    int t = threadIdx.x, lane = t & 63, wave = t >> 6;
    int wm = wave >> 2, wn = wave & 3;          // 2 x 4 wave grid, wave tile 128x64
    int fr = lane & 15, fq = lane >> 4;

    // ---- stage source: row = t>>2 (+128 for instr1), slot pre-swizzled ----
    int srow = t >> 2;                                   // 0..127
    int slotg = (t & 3) ^ ((srow ^ (srow >> 2)) & 3);    // involution of read swizzle
    const ushort_t* sA = A  + (size_t)srow * ND + slotg * 8;
    const ushort_t* sB = Bt + (size_t)srow * ND + slotg * 8;
    int ldst = t * 8;                                    // ushort offset (instr0); +4096 instr1

    // ---- read-side fragment byte offsets within a [256][32] half-tile ----
    int swzb = (fq ^ ((fr ^ (fr >> 2)) & 3)) * 16;       // conflict-free 16B slot
    int aoff[8], boff[4];
#pragma unroll
    for (int mi = 0; mi < 8; ++mi) aoff[mi] = (wm * 128 + mi * 16 + fr) * 64 + swzb;
#pragma unroll
    for (int nj = 0; nj < 4; ++nj) boff[nj] = (wn * 64 + nj * 16 + fr) * 64 + swzb;

    f32x4 acc[8][4];
#pragma unroll
    for (int i = 0; i < 8; ++i)
#pragma unroll
        for (int j = 0; j < 4; ++j) acc[i][j] = (f32x4){0.f, 0.f, 0.f, 0.f};

    const int NT = ND / 64;   // 16 K-tiles

#define STG_A(kh, ktt, bf) do { \
    gload16(sA + (ktt) * 64 + (kh) * 32,            &ldsA[bf][kh][ldst]); \
    gload16(sA + (ktt) * 64 + (kh) * 32 + 128 * ND, &ldsA[bf][kh][4096 + ldst]); \
} while (0)
#define STG_B(kh, ktt, bf) do { \
    gload16(sB + (ktt) * 64 + (kh) * 32,            &ldsB[bf][kh][ldst]); \
    gload16(sB + (ktt) * 64 + (kh) * 32 + 128 * ND, &ldsB[bf][kh][4096 + ldst]); \
} while (0)
#define PH_GATE do { \
    __builtin_amdgcn_sched_barrier(0); \
    __builtin_amdgcn_s_barrier(); \
    asm volatile("s_waitcnt lgkmcnt(0)" ::: "memory"); \
    __builtin_amdgcn_sched_barrier(0); \
} while (0)
#define MFMA16(base, aR, bR) do { \
    __builtin_amdgcn_s_setprio(1); \
    _Pragma("unroll") \
    for (int mi = 0; mi < 4; ++mi) \
        _Pragma("unroll") \
        for (int nj = 0; nj < 4; ++nj) \
            acc[(base) + mi][nj] = __builtin_amdgcn_mfma_f32_16x16x32_bf16(aR[mi], bR[nj], acc[(base) + mi][nj], 0, 0, 0); \
    __builtin_amdgcn_s_setprio(0); \
    __builtin_amdgcn_sched_barrier(0); \
} while (0)

    // ---- prologue: stage A0,B0,A1,B1 of t0 + A0,B0 of t1; first two landed ----
    STG_A(0, 0, 0); STG_B(0, 0, 0); STG_A(1, 0, 0); STG_B(1, 0, 0);
    STG_A(0, 1, 1); STG_B(0, 1, 1);
    asm volatile("s_waitcnt vmcnt(8)" ::: "memory");
    __builtin_amdgcn_s_barrier();

    for (int kt = 0; kt < NT; ++kt) {
        int buf = kt & 1, nb = buf ^ 1;
        const char* lA0 = (const char*)&ldsA[buf][0][0];
        const char* lA1 = (const char*)&ldsA[buf][1][0];
        const char* lB0 = (const char*)&ldsB[buf][0][0];
        const char* lB1 = (const char*)&ldsB[buf][1][0];
        bf16x8 aX[4], aY[4], bX[4], bY[4];

        // ---- ph0: kk=0, mi 0..3 ; stage A-Kh1(kt+1) ----
#pragma unroll
        for (int nj = 0; nj < 4; ++nj) bX[nj] = *(const bf16x8*)(lB0 + boff[nj]);
#pragma unroll
        for (int mi = 0; mi < 4; ++mi) aX[mi] = *(const bf16x8*)(lA0 + aoff[mi]);
        if (kt + 1 < NT) STG_A(1, kt + 1, nb);
        PH_GATE;
        MFMA16(0, aX, bX);
        __builtin_amdgcn_s_barrier();

        // ---- ph1: kk=0, mi 4..7 (bX reused); stage B-Kh1(kt+1); vmcnt ----
#pragma unroll
        for (int mi = 0; mi < 4; ++mi) aY[mi] = *(const bf16x8*)(lA0 + aoff[mi + 4]);
        if (kt + 1 < NT) STG_B(1, kt + 1, nb);
        PH_GATE;
        MFMA16(4, aY, bX);
        if (kt < NT - 1) asm volatile("s_waitcnt vmcnt(8)" ::: "memory");
        else             asm volatile("s_waitcnt vmcnt(0)" ::: "memory");
        __builtin_amdgcn_s_barrier();

        // ---- ph2: kk=1, mi 0..3 ; stage A-Kh0(kt+2) ----
#pragma unroll
        for (int nj = 0; nj < 4; ++nj) bY[nj] = *(const bf16x8*)(lB1 + boff[nj]);
#pragma unroll
        for (int mi = 0; mi < 4; ++mi) aX[mi] = *(const bf16x8*)(lA1 + aoff[mi]);
        if (kt + 2 < NT) STG_A(0, kt + 2, buf);
        PH_GATE;
        MFMA16(0, aX, bY);
        __builtin_amdgcn_s_barrier();

        // ---- ph3: kk=1, mi 4..7 (bY reused); stage B-Kh0(kt+2); vmcnt ----
#pragma unroll
        for (int mi = 0; mi < 4; ++mi) aY[mi] = *(const bf16x8*)(lA1 + aoff[mi + 4]);
        if (kt + 2 < NT) STG_B(0, kt + 2, buf);
        PH_GATE;
        MFMA16(4, aY, bY);
        if (kt < NT - 2)       asm volatile("s_waitcnt vmcnt(8)" ::: "memory");
        else if (kt == NT - 2) asm volatile("s_waitcnt vmcnt(4)" ::: "memory");
        if (kt < NT - 1) __builtin_amdgcn_s_barrier();
    }

#undef STG_A
#undef STG_B
#undef PH_GATE
#undef MFMA16

    // ---- epilogue: bias + fp32 store ----
    const float* bs = bias + b * ND;
    float* O = out + ((size_t)b * NS * ND);
#pragma unroll
    for (int mi = 0; mi < 8; ++mi) {
        int row = m0 + wm * 128 + mi * 16 + fq * 4;
#pragma unroll
        for (int nj = 0; nj < 4; ++nj) {
            int col = n0 + wn * 64 + nj * 16 + fr;
            float bv = bs[col];
            f32x4 v = acc[mi][nj];
#pragma unroll
            for (int r = 0; r < 4; ++r)
                O[(size_t)(row + r) * ND + col] = v[r] + bv;
        }
    }
}

extern "C" void kernel_launch(void* const* d_in, const int* in_sizes, int n_in,
                              void* d_out, int out_size, void* d_ws, size_t ws_size,
                              hipStream_t stream) {
    const float* x      = (const float*)d_in[0];
    const float* scores = (const float*)d_in[1];
    const float* Wx     = (const float*)d_in[2];
    const float* eb     = (const float*)d_in[3];
    const int*   kp     = (const int*)d_in[4];
    float* out = (float*)d_out;
    char* ws = (char*)d_ws;

    float*    bias  = (float*)(ws + 1024);
    ushort_t* xbuf  = (ushort_t*)(ws + 65536);
    ushort_t* wct   = (ushort_t*)(ws + 65536 + (size_t)NB * NS * ND * 2);
    float*    counts = out + (size_t)NB * NS * ND;

    prep_kernel<<<10273, 256, 0, stream>>>(x, scores, Wx, eb, kp, xbuf, wct, bias, counts);
    gemm_kernel<<<256, 512, 0, stream>>>(xbuf, wct, bias, out);
}

// Round 9
// 67.527 us; speedup vs baseline: 1.0584x; 1.0584x over previous
//
#include <hip/hip_runtime.h>

#define NB 8
#define NS 2048
#define ND 1024
#define NE 8

typedef unsigned short ushort_t;
typedef __attribute__((ext_vector_type(8))) short bf16x8;
typedef __attribute__((ext_vector_type(4))) float f32x4;

__device__ __forceinline__ unsigned short f2bf(float f) {
    union { float f; unsigned int u; } x; x.f = f;
    unsigned int u = x.u + 0x7fffu + ((x.u >> 16) & 1u);
    return (unsigned short)(u >> 16);
}

__device__ __forceinline__ void gload16(const void* g, void* l) {
    __builtin_amdgcn_global_load_lds(
        (const __attribute__((address_space(1))) unsigned int*)g,
        (__attribute__((address_space(3))) unsigned int*)l, 16, 0, 0);
}

// local top-k gate coefs for one batch row (deterministic tie-break = first index)
__device__ __forceinline__ void coef_local(const float* __restrict__ scores,
                                           int b, int k, float* cf) {
    float s[NE];
#pragma unroll
    for (int e = 0; e < NE; ++e) s[e] = scores[b * NE + e];
    bool sel[NE];
#pragma unroll
    for (int e = 0; e < NE; ++e) sel[e] = false;
    float sum = 0.f;
    for (int j = 0; j < k; ++j) {
        int best = 0; float bv = -3.4e38f;
#pragma unroll
        for (int e = 0; e < NE; ++e)
            if (!sel[e] && s[e] > bv) { bv = s[e]; best = e; }
        sel[best] = true; sum += bv;
    }
    float scale = 1.f / (sum + 1e-8f);
#pragma unroll
    for (int e = 0; e < NE; ++e) cf[e] = sel[e] ? scale * s[e] : 0.f;
}

// ====== fused prep: combine (2048 blk) | convert (8192 blk) | bias (32) | routing (1) ======
__global__ void prep_kernel(const float* __restrict__ x,
                            const float* __restrict__ scores,
                            const float* __restrict__ W,
                            const float* __restrict__ eb,
                            const int* __restrict__ kp,
                            ushort_t* __restrict__ xb,
                            ushort_t* __restrict__ wct,
                            float* __restrict__ bias,
                            float* __restrict__ counts) {
    __shared__ float tile[64][65];
    __shared__ int selS[NB][NE];
    int bid = blockIdx.x;
    int t = threadIdx.x;

    if (bid < 2048) {
        int b = bid >> 8;
        int f0 = (bid & 15) * 64, d0 = ((bid >> 4) & 15) * 64;
        float cf[NE];
        coef_local(scores, b, kp[0], cf);
        int lr = t >> 4;
        int lc = (t & 15) * 4;
        float4 acc[4];
#pragma unroll
        for (int it = 0; it < 4; ++it) acc[it] = make_float4(0.f, 0.f, 0.f, 0.f);
#pragma unroll
        for (int e = 0; e < NE; ++e) {
            float c = cf[e];
            if (c != 0.f) {
                const float* We = W + ((size_t)e * ND * ND);
#pragma unroll
                for (int it = 0; it < 4; ++it) {
                    int d = d0 + lr + it * 16;
                    float4 v = *(const float4*)(We + (size_t)d * ND + f0 + lc);
                    acc[it].x += c * v.x; acc[it].y += c * v.y;
                    acc[it].z += c * v.z; acc[it].w += c * v.w;
                }
            }
        }
#pragma unroll
        for (int it = 0; it < 4; ++it) {
            int r = lr + it * 16;
            tile[r][lc + 0] = acc[it].x; tile[r][lc + 1] = acc[it].y;
            tile[r][lc + 2] = acc[it].z; tile[r][lc + 3] = acc[it].w;
        }
        __syncthreads();
        int dl = t & 63;
        int frow = t >> 6;
        ushort_t* dst = wct + (size_t)b * ND * ND + (size_t)f0 * ND + d0 + dl;
#pragma unroll
        for (int it = 0; it < 16; ++it) {
            int f = frow + it * 4;
            dst[(size_t)f * ND] = f2bf(tile[dl][f]);
        }
    } else if (bid < 10240) {
        size_t i = (size_t)(bid - 2048) * 256 + t;
        const float4* p = (const float4*)x + 2 * i;
        float4 a = p[0], b = p[1];
        uint4 o;
        o.x = (unsigned)f2bf(a.x) | ((unsigned)f2bf(a.y) << 16);
        o.y = (unsigned)f2bf(a.z) | ((unsigned)f2bf(a.w) << 16);
        o.z = (unsigned)f2bf(b.x) | ((unsigned)f2bf(b.y) << 16);
        o.w = (unsigned)f2bf(b.z) | ((unsigned)f2bf(b.w) << 16);
        ((uint4*)xb)[i] = o;
    } else if (bid < 10272) {
        int i = bid - 10240;
        int b = i >> 2, f = (i & 3) * 256 + t;
        float cf[NE];
        coef_local(scores, b, kp[0], cf);
        float acc = 0.f;
#pragma unroll
        for (int e = 0; e < NE; ++e)
            if (cf[e] != 0.f) acc += cf[e] * eb[e * ND + f];
        bias[b * ND + f] = acc;
    } else {
        int k = kp[0];
        if (t < NB) {
            float s[NE];
#pragma unroll
            for (int e = 0; e < NE; ++e) s[e] = scores[t * NE + e];
            bool sel[NE];
#pragma unroll
            for (int e = 0; e < NE; ++e) sel[e] = false;
            for (int j = 0; j < k; ++j) {
                int best = 0; float bv = -3.4e38f;
#pragma unroll
                for (int e = 0; e < NE; ++e)
                    if (!sel[e] && s[e] > bv) { bv = s[e]; best = e; }
                sel[best] = true;
            }
#pragma unroll
            for (int e = 0; e < NE; ++e) selS[t][e] = sel[e] ? 1 : 0;
        }
        __syncthreads();
        if (t < NE) {
            int c = 0;
#pragma unroll
            for (int b = 0; b < NB; ++b) c += selS[b][t];
            counts[t] = (float)c;
        }
    }
}

// ====== 256x128 8-wave GEMM, BK=32, 3-buffer LDS (72 KiB) => 2 blocks/CU ======
// Cross-block wave overlap hides lgkm/barrier stalls (m97/m114 mechanism).
// Counted vmcnt(3): stage tile t+2 each iter, never drain-0 in steady state.
__global__ __launch_bounds__(512, 4) void gemm_kernel(const ushort_t* __restrict__ xb,
                                                      const ushort_t* __restrict__ wct,
                                                      const float* __restrict__ bias,
                                                      float* __restrict__ out) {
    __shared__ ushort_t ldsA[3][256 * 32];   // 48 KiB
    __shared__ ushort_t ldsB[3][128 * 32];   // 24 KiB

    int bid = blockIdx.x;
    int b = bid & 7;                 // batch -> XCD (round-robin % 8)
    int tile = bid >> 3;             // 0..63
    int m0 = (tile >> 3) * 256;      // 8 M-tiles
    int n0 = (tile & 7) * 128;       // 8 N-tiles
    const ushort_t* A  = xb  + ((size_t)b * NS * ND) + (size_t)m0 * ND;
    const ushort_t* Bt = wct + ((size_t)b * ND * ND) + (size_t)n0 * ND;

    int t = threadIdx.x, lane = t & 63, wave = t >> 6;
    int wm = wave >> 1, wn = wave & 1;          // 4 x 2 wave grid, wave tile 64x64
    int fr = lane & 15, fq = lane >> 4;

    // ---- staging source (pre-swizzled: slot ^= (row>>1)&3; LDS dest linear) ----
    int srow = t >> 2;                               // 0..127
    int slotg = (t & 3) ^ ((srow >> 1) & 3);
    const ushort_t* sA = A  + (size_t)srow * ND + slotg * 8;
    const ushort_t* sB = Bt + (size_t)srow * ND + slotg * 8;
    int ldst = t * 8;                                // ushort offset; A instr1 at +4096 (rows 128..255)

    // ---- read-side fragment byte offsets (R7-proven 0-conflict swizzle) ----
    int swzb = (fq ^ ((fr >> 1) & 3)) * 16;
    int aoff[4], boff[4];
#pragma unroll
    for (int mi = 0; mi < 4; ++mi) aoff[mi] = (wm * 64 + mi * 16 + fr) * 64 + swzb;
#pragma unroll
    for (int nj = 0; nj < 4; ++nj) boff[nj] = (wn * 64 + nj * 16 + fr) * 64 + swzb;

    f32x4 acc[4][4];
#pragma unroll
    for (int i = 0; i < 4; ++i)
#pragma unroll
        for (int j = 0; j < 4; ++j) acc[i][j] = (f32x4){0.f, 0.f, 0.f, 0.f};

    const int NT = ND / 32;   // 32 K-tiles

#define STAGE(kt, buf) do { \
    gload16(sA + (kt) * 32,            &ldsA[buf][ldst]); \
    gload16(sA + (kt) * 32 + 128 * ND, &ldsA[buf][4096 + ldst]); \
    gload16(sB + (kt) * 32,            &ldsB[buf][ldst]); \
} while (0)

    // ---- prologue: stage tiles 0,1 -> bufs 0,1 ----
    STAGE(0, 0);
    STAGE(1, 1);
    asm volatile("s_waitcnt vmcnt(3)" ::: "memory");   // tile 0 landed
    __builtin_amdgcn_s_barrier();

    int cur = 0;
    for (int kt = 0; kt < NT; ++kt) {
        const char* lA = (const char*)&ldsA[cur][0];
        const char* lB = (const char*)&ldsB[cur][0];
        int sq = cur + 2; if (sq >= 3) sq -= 3;        // buffer for tile kt+2

        __builtin_amdgcn_sched_barrier(0);
        bf16x8 af[4], bf[4];
#pragma unroll
        for (int nj = 0; nj < 4; ++nj) bf[nj] = *(const bf16x8*)(lB + boff[nj]);
#pragma unroll
        for (int mi = 0; mi < 4; ++mi) af[mi] = *(const bf16x8*)(lA + aoff[mi]);
        if (kt + 2 < NT) STAGE(kt + 2, sq);
        __builtin_amdgcn_sched_barrier(0);
        asm volatile("s_waitcnt lgkmcnt(0)" ::: "memory");
        __builtin_amdgcn_sched_barrier(0);
        __builtin_amdgcn_s_setprio(1);
#pragma unroll
        for (int mi = 0; mi < 4; ++mi)
#pragma unroll
            for (int nj = 0; nj < 4; ++nj)
                acc[mi][nj] = __builtin_amdgcn_mfma_f32_16x16x32_bf16(af[mi], bf[nj], acc[mi][nj], 0, 0, 0);
        __builtin_amdgcn_s_setprio(0);
        __builtin_amdgcn_sched_barrier(0);
        // counted wait: tile kt+1's 3 loads landed; kt+2's 3 stay in flight
        if (kt + 2 < NT) {
            asm volatile("s_waitcnt vmcnt(3)" ::: "memory");
        } else if (kt + 1 < NT) {
            asm volatile("s_waitcnt vmcnt(0)" ::: "memory");
        }
        if (kt + 1 < NT) __builtin_amdgcn_s_barrier();
        cur += 1; if (cur == 3) cur = 0;
    }

#undef STAGE

    // ---- epilogue: bias + fp32 store ----
    const float* bs = bias + b * ND;
    float* O = out + ((size_t)b * NS * ND);
#pragma unroll
    for (int mi = 0; mi < 4; ++mi) {
        int row = m0 + wm * 64 + mi * 16 + fq * 4;
#pragma unroll
        for (int nj = 0; nj < 4; ++nj) {
            int col = n0 + wn * 64 + nj * 16 + fr;
            float bv = bs[col];
            f32x4 v = acc[mi][nj];
#pragma unroll
            for (int r = 0; r < 4; ++r)
                O[(size_t)(row + r) * ND + col] = v[r] + bv;
        }
    }
}

extern "C" void kernel_launch(void* const* d_in, const int* in_sizes, int n_in,
                              void* d_out, int out_size, void* d_ws, size_t ws_size,
                              hipStream_t stream) {
    const float* x      = (const float*)d_in[0];
    const float* scores = (const float*)d_in[1];
    const float* Wx     = (const float*)d_in[2];
    const float* eb     = (const float*)d_in[3];
    const int*   kp     = (const int*)d_in[4];
    float* out = (float*)d_out;
    char* ws = (char*)d_ws;

    float*    bias  = (float*)(ws + 1024);
    ushort_t* xbuf  = (ushort_t*)(ws + 65536);
    ushort_t* wct   = (ushort_t*)(ws + 65536 + (size_t)NB * NS * ND * 2);
    float*    counts = out + (size_t)NB * NS * ND;

    prep_kernel<<<10273, 256, 0, stream>>>(x, scores, Wx, eb, kp, xbuf, wct, bias, counts);
    gemm_kernel<<<512, 512, 0, stream>>>(xbuf, wct, bias, out);
}